// Round 2
// baseline (825.556 us; speedup 1.0000x reference)
//
#include <hip/hip_runtime.h>
#include <stdint.h>

// R2: dual-dtype (fp32/bf16 inputs auto-detected on device) fused GNN layer.
// Structure: probe -> ln -> ltl -> pack(w x4) -> cnt -> edge MLP (MFMA, scatter-add) -> node MLP (MFMA, residual).

#define N_NODES 100000
#define N_GRAPH 5000
#define N_EDGE  1000000
#define H 128

typedef unsigned short u16;
typedef __attribute__((ext_vector_type(8))) short short8;
typedef __attribute__((ext_vector_type(4))) float floatx4;

__device__ inline float b2f(u16 x) {
    unsigned u = ((unsigned)x) << 16;
    return __uint_as_float(u);
}
__device__ inline u16 f2b(float f) {
    unsigned u = __float_as_uint(f);
    unsigned r = (u + 0x7FFFu + ((u >> 16) & 1u)) >> 16;  // RNE
    return (u16)r;
}
__device__ inline float silu_f(float x) {
    x = fminf(30.f, fmaxf(-30.f, x));   // also masks any stray NaN/inf
    return x / (1.0f + __expf(-x));
}

// ---------------- dtype probe: flag=1 if inputs are bf16, 0 if fp32 ----------------
__global__ void probe_kernel(const unsigned* __restrict__ nf_raw, int* __restrict__ flag) {
    __shared__ int cnt_s;
    if (threadIdx.x == 0) cnt_s = 0;
    __syncthreads();
    unsigned u = nf_raw[threadIdx.x];
    unsigned e2 = (u >> 7) & 0xFF;   // exponent of LOW-half bf16 if data is bf16 pairs
    int in_range = (e2 >= 90 && e2 <= 160) ? 1 : 0;
    atomicAdd(&cnt_s, in_range);
    __syncthreads();
    if (threadIdx.x == 0) *flag = (cnt_s >= 128) ? 1 : 0;
}

// ---------------- LayerNorm: h = LN(node_features) * g + b, bf16 out ----------------
__global__ void ln_kernel(const void* __restrict__ nf, const void* __restrict__ g,
                          const void* __restrict__ b, u16* __restrict__ h,
                          const int* __restrict__ flagp) {
    int bf = *flagp;
    int row = blockIdx.x * 4 + (threadIdx.x >> 6);
    int lane = threadIdx.x & 63;
    if (row >= N_NODES) return;
    float x0, x1;
    if (bf) {
        unsigned v = ((const unsigned*)nf)[(size_t)row * 64 + lane];
        x0 = b2f((u16)(v & 0xFFFF));
        x1 = b2f((u16)(v >> 16));
    } else {
        const float* p = (const float*)nf + (size_t)row * H + lane * 2;
        x0 = p[0]; x1 = p[1];
    }
    float s1 = x0 + x1, s2 = x0 * x0 + x1 * x1;
    #pragma unroll
    for (int off = 32; off >= 1; off >>= 1) {
        s1 += __shfl_xor(s1, off, 64);
        s2 += __shfl_xor(s2, off, 64);
    }
    float mu = s1 * (1.0f / H);
    float var = s2 * (1.0f / H) - mu * mu;
    float rs = rsqrtf(var + 1e-5f);
    float g0, g1, bb0, bb1;
    if (bf) {
        unsigned gv = ((const unsigned*)g)[lane];
        unsigned bv = ((const unsigned*)b)[lane];
        g0 = b2f((u16)(gv & 0xFFFF)); g1 = b2f((u16)(gv >> 16));
        bb0 = b2f((u16)(bv & 0xFFFF)); bb1 = b2f((u16)(bv >> 16));
    } else {
        g0 = ((const float*)g)[lane * 2]; g1 = ((const float*)g)[lane * 2 + 1];
        bb0 = ((const float*)b)[lane * 2]; bb1 = ((const float*)b)[lane * 2 + 1];
    }
    float y0 = (x0 - mu) * rs * g0 + bb0;
    float y1 = (x1 - mu) * rs * g1 + bb1;
    unsigned o = (unsigned)f2b(y0) | ((unsigned)f2b(y1) << 16);
    *(unsigned*)(h + (size_t)row * H + lane * 2) = o;
}

// ---------------- ltl[g] = L @ L^T flattened to 9, stored bf16 stride 12 ----------------
__global__ void ltl_kernel(const void* __restrict__ lat, u16* __restrict__ latb,
                           const int* __restrict__ flagp) {
    int bf = *flagp;
    int idx = blockIdx.x * 256 + threadIdx.x;
    if (idx >= N_GRAPH * 9) return;
    int gi = idx / 9, ij = idx - gi * 9;
    int i = ij / 3, j = ij - i * 3;
    float s = 0.f;
    if (bf) {
        const u16* Lg = (const u16*)lat + gi * 9;
        #pragma unroll
        for (int k = 0; k < 3; k++) s += b2f(Lg[i * 3 + k]) * b2f(Lg[j * 3 + k]);
    } else {
        const float* Lg = (const float*)lat + gi * 9;
        #pragma unroll
        for (int k = 0; k < 3; k++) s += Lg[i * 3 + k] * Lg[j * 3 + k];
    }
    latb[gi * 12 + ij] = f2b(s);
}

// ---------------- pack W [Ksrc,128] row-major -> MFMA B-fragment layout ----------------
// out[((kt*8+nt)*64+lane)*8 + j] = W[kt*32 + (lane>>4)*8 + j][nt*16 + (lane&15)], 0 if k>=Ksrc
__global__ void pack_kernel(const void* __restrict__ W, u16* __restrict__ out, int Ksrc, int KT,
                            const int* __restrict__ flagp) {
    int bf = *flagp;
    int t = blockIdx.x * 256 + threadIdx.x;
    if (t >= KT * 8 * 64) return;
    int lane = t & 63, nt = (t >> 6) & 7, kt = t >> 9;
    int n = nt * 16 + (lane & 15);
    int kbase = kt * 32 + ((lane >> 4) << 3);
    u16 vals[8];
    #pragma unroll
    for (int j = 0; j < 8; j++) {
        int k = kbase + j;
        if (k >= Ksrc) vals[j] = 0;
        else if (bf) vals[j] = ((const u16*)W)[(size_t)k * H + n];
        else vals[j] = f2b(((const float*)W)[(size_t)k * H + n]);
    }
    uint4 tmp;
    __builtin_memcpy(&tmp, vals, 16);
    *(uint4*)(out + (size_t)t * 8) = tmp;
}

// ---------------- in-degree counts over edge_index[0] ----------------
__global__ void cnt_kernel(const int* __restrict__ ei, int* __restrict__ cnt) {
    int e = blockIdx.x * 256 + threadIdx.x;
    if (e < N_EDGE) atomicAdd(&cnt[ei[e]], 1);
}

// ---------------- fused edge MLP + scatter-add ----------------
#define EKP 296   // A-tile row stride (bf16) for K=288
#define PP  136   // intermediate tile stride

__global__ __launch_bounds__(256, 2) void edge_kernel(
    const u16* __restrict__ h, const u16* __restrict__ latb,
    const int* __restrict__ ei, const int* __restrict__ e2g,
    const void* __restrict__ fd,
    const u16* __restrict__ W1p, const u16* __restrict__ W2p,
    const void* __restrict__ bias1, const void* __restrict__ bias2,
    float* __restrict__ agg, const int* __restrict__ flagp) {
    __shared__ u16 sA[64 * EKP];
    __shared__ u16 sP[64 * PP];
    __shared__ int sSrc[64], sDst[64], sG[64];
    __shared__ float sB1[128], sB2[128];

    int bf = *flagp;
    int tid = threadIdx.x;
    int lane = tid & 63, w = tid >> 6;
    int e0 = blockIdx.x * 64;

    if (tid < 64) {
        sSrc[tid] = ei[e0 + tid];
        sDst[tid] = ei[N_EDGE + e0 + tid];
        sG[tid] = e2g[e0 + tid];
    }
    if (tid < 128) sB1[tid] = bf ? b2f(((const u16*)bias1)[tid]) : ((const float*)bias1)[tid];
    else sB2[tid - 128] = bf ? b2f(((const u16*)bias2)[tid - 128]) : ((const float*)bias2)[tid - 128];
    __syncthreads();

    // gather hi | hj (16B chunks) from internal bf16 h
    for (int i = tid; i < 2048; i += 256) {
        int row = i >> 5, c = i & 31;
        int node = (c < 16) ? sSrc[row] : sDst[row];
        int cc = c & 15;
        uint4 v = *(const uint4*)(h + (size_t)node * H + cc * 8);
        *(uint4*)(&sA[row * EKP + c * 8]) = v;
    }
    // lat(9) + fd(3) + zero pad(20)
    if (tid < 64) {
        int row = tid;
        int g = sG[row];
        u16* dst = &sA[row * EKP + 256];
        #pragma unroll
        for (int j = 0; j < 9; j++) dst[j] = latb[g * 12 + j];
        if (bf) {
            const u16* f = (const u16*)fd + (size_t)(e0 + row) * 3;
            dst[9] = f[0]; dst[10] = f[1]; dst[11] = f[2];
        } else {
            const float* f = (const float*)fd + (size_t)(e0 + row) * 3;
            dst[9] = f2b(f[0]); dst[10] = f2b(f[1]); dst[11] = f2b(f[2]);
        }
        #pragma unroll
        for (int j = 12; j < 32; j++) dst[j] = 0;
    }
    __syncthreads();

    const short8* W1v = (const short8*)W1p;
    const short8* W2v = (const short8*)W2p;
    int q8 = (lane >> 4) * 8;
    int mrow = lane & 15;
    int q = lane >> 4;

    // ---- layer 1: [64,288] @ [288,128], wave w owns cols w*32..w*32+31 ----
    floatx4 acc[4][2];
    #pragma unroll
    for (int mt = 0; mt < 4; mt++) {
        acc[mt][0] = (floatx4){0.f, 0.f, 0.f, 0.f};
        acc[mt][1] = (floatx4){0.f, 0.f, 0.f, 0.f};
    }
    #pragma unroll
    for (int kt = 0; kt < 9; kt++) {
        short8 bf0 = W1v[(kt * 8 + 2 * w) * 64 + lane];
        short8 bf1 = W1v[(kt * 8 + 2 * w + 1) * 64 + lane];
        #pragma unroll
        for (int mt = 0; mt < 4; mt++) {
            short8 a = *(const short8*)(&sA[(mt * 16 + mrow) * EKP + kt * 32 + q8]);
            acc[mt][0] = __builtin_amdgcn_mfma_f32_16x16x32_bf16(a, bf0, acc[mt][0], 0, 0, 0);
            acc[mt][1] = __builtin_amdgcn_mfma_f32_16x16x32_bf16(a, bf1, acc[mt][1], 0, 0, 0);
        }
    }
    // epilogue 1: bias + silu -> sP (bf16)
    #pragma unroll
    for (int mt = 0; mt < 4; mt++) {
        #pragma unroll
        for (int nt = 0; nt < 2; nt++) {
            int n = w * 32 + nt * 16 + mrow;
            float bias = sB1[n];
            #pragma unroll
            for (int r = 0; r < 4; r++) {
                int row = mt * 16 + q * 4 + r;
                sP[row * PP + n] = f2b(silu_f(acc[mt][nt][r] + bias));
            }
        }
    }
    __syncthreads();

    // ---- layer 2: [64,128] @ [128,128] ----
    floatx4 acc2[4][2];
    #pragma unroll
    for (int mt = 0; mt < 4; mt++) {
        acc2[mt][0] = (floatx4){0.f, 0.f, 0.f, 0.f};
        acc2[mt][1] = (floatx4){0.f, 0.f, 0.f, 0.f};
    }
    #pragma unroll
    for (int kt = 0; kt < 4; kt++) {
        short8 bf0 = W2v[(kt * 8 + 2 * w) * 64 + lane];
        short8 bf1 = W2v[(kt * 8 + 2 * w + 1) * 64 + lane];
        #pragma unroll
        for (int mt = 0; mt < 4; mt++) {
            short8 a = *(const short8*)(&sP[(mt * 16 + mrow) * PP + kt * 32 + q8]);
            acc2[mt][0] = __builtin_amdgcn_mfma_f32_16x16x32_bf16(a, bf0, acc2[mt][0], 0, 0, 0);
            acc2[mt][1] = __builtin_amdgcn_mfma_f32_16x16x32_bf16(a, bf1, acc2[mt][1], 0, 0, 0);
        }
    }
    // epilogue 2: bias + silu -> atomic scatter into agg[src]
    #pragma unroll
    for (int mt = 0; mt < 4; mt++) {
        #pragma unroll
        for (int nt = 0; nt < 2; nt++) {
            int n = w * 32 + nt * 16 + mrow;
            float bias = sB2[n];
            #pragma unroll
            for (int r = 0; r < 4; r++) {
                int row = mt * 16 + q * 4 + r;
                float s = silu_f(acc2[mt][nt][r] + bias);
                atomicAdd(&agg[(size_t)sSrc[row] * H + n], s);
            }
        }
    }
}

// ---------------- node MLP + residual ----------------
#define NKP 264   // A-tile row stride for K=256

__global__ __launch_bounds__(256, 2) void node_kernel(
    const u16* __restrict__ h, const float* __restrict__ agg, const int* __restrict__ cnt,
    const void* __restrict__ nf,
    const u16* __restrict__ W1p, const u16* __restrict__ W2p,
    const void* __restrict__ bias1, const void* __restrict__ bias2,
    void* __restrict__ out, const int* __restrict__ flagp) {
    __shared__ u16 sA[64 * NKP];
    __shared__ u16 sP[64 * PP];
    __shared__ float sB1[128], sB2[128];

    int bf = *flagp;
    int tid = threadIdx.x;
    int lane = tid & 63, w = tid >> 6;
    int r0 = blockIdx.x * 64;

    if (tid < 128) sB1[tid] = bf ? b2f(((const u16*)bias1)[tid]) : ((const float*)bias1)[tid];
    else sB2[tid - 128] = bf ? b2f(((const u16*)bias2)[tid - 128]) : ((const float*)bias2)[tid - 128];

    // stage h rows (cols 0..127)
    for (int i = tid; i < 1024; i += 256) {
        int row = i >> 4, c = i & 15;
        int gr = r0 + row; if (gr >= N_NODES) gr = N_NODES - 1;
        uint4 v = *(const uint4*)(h + (size_t)gr * H + c * 8);
        *(uint4*)(&sA[row * NKP + c * 8]) = v;
    }
    // stage agg/cnt rows (cols 128..255), fp32 -> bf16
    for (int i = tid; i < 2048; i += 256) {
        int row = i >> 5, c = i & 31;
        int gr = r0 + row; if (gr >= N_NODES) gr = N_NODES - 1;
        int cn = cnt[gr];
        float sc = 1.0f / (float)(cn > 0 ? cn : 1);
        const float* ap = agg + (size_t)gr * H + c * 4;
        u16 vv[4];
        #pragma unroll
        for (int j = 0; j < 4; j++) vv[j] = f2b(ap[j] * sc);
        uint2 tmp;
        __builtin_memcpy(&tmp, vv, 8);
        *(uint2*)(&sA[row * NKP + 128 + c * 4]) = tmp;
    }
    __syncthreads();

    const short8* W1v = (const short8*)W1p;
    const short8* W2v = (const short8*)W2p;
    int q8 = (lane >> 4) * 8;
    int mrow = lane & 15;
    int q = lane >> 4;

    floatx4 acc[4][2];
    #pragma unroll
    for (int mt = 0; mt < 4; mt++) {
        acc[mt][0] = (floatx4){0.f, 0.f, 0.f, 0.f};
        acc[mt][1] = (floatx4){0.f, 0.f, 0.f, 0.f};
    }
    #pragma unroll
    for (int kt = 0; kt < 8; kt++) {
        short8 bf0 = W1v[(kt * 8 + 2 * w) * 64 + lane];
        short8 bf1 = W1v[(kt * 8 + 2 * w + 1) * 64 + lane];
        #pragma unroll
        for (int mt = 0; mt < 4; mt++) {
            short8 a = *(const short8*)(&sA[(mt * 16 + mrow) * NKP + kt * 32 + q8]);
            acc[mt][0] = __builtin_amdgcn_mfma_f32_16x16x32_bf16(a, bf0, acc[mt][0], 0, 0, 0);
            acc[mt][1] = __builtin_amdgcn_mfma_f32_16x16x32_bf16(a, bf1, acc[mt][1], 0, 0, 0);
        }
    }
    #pragma unroll
    for (int mt = 0; mt < 4; mt++) {
        #pragma unroll
        for (int nt = 0; nt < 2; nt++) {
            int n = w * 32 + nt * 16 + mrow;
            float bias = sB1[n];
            #pragma unroll
            for (int r = 0; r < 4; r++) {
                int row = mt * 16 + q * 4 + r;
                sP[row * PP + n] = f2b(silu_f(acc[mt][nt][r] + bias));
            }
        }
    }
    __syncthreads();

    floatx4 acc2[4][2];
    #pragma unroll
    for (int mt = 0; mt < 4; mt++) {
        acc2[mt][0] = (floatx4){0.f, 0.f, 0.f, 0.f};
        acc2[mt][1] = (floatx4){0.f, 0.f, 0.f, 0.f};
    }
    #pragma unroll
    for (int kt = 0; kt < 4; kt++) {
        short8 bf0 = W2v[(kt * 8 + 2 * w) * 64 + lane];
        short8 bf1 = W2v[(kt * 8 + 2 * w + 1) * 64 + lane];
        #pragma unroll
        for (int mt = 0; mt < 4; mt++) {
            short8 a = *(const short8*)(&sP[(mt * 16 + mrow) * PP + kt * 32 + q8]);
            acc2[mt][0] = __builtin_amdgcn_mfma_f32_16x16x32_bf16(a, bf0, acc2[mt][0], 0, 0, 0);
            acc2[mt][1] = __builtin_amdgcn_mfma_f32_16x16x32_bf16(a, bf1, acc2[mt][1], 0, 0, 0);
        }
    }
    #pragma unroll
    for (int mt = 0; mt < 4; mt++) {
        #pragma unroll
        for (int nt = 0; nt < 2; nt++) {
            int n = w * 32 + nt * 16 + mrow;
            float bias = sB2[n];
            #pragma unroll
            for (int r = 0; r < 4; r++) {
                int row = mt * 16 + q * 4 + r;
                int gr = r0 + row;
                if (gr < N_NODES) {
                    float s = silu_f(acc2[mt][nt][r] + bias);
                    size_t idx = (size_t)gr * H + n;
                    float nv = bf ? b2f(((const u16*)nf)[idx]) : ((const float*)nf)[idx];
                    float o = nv + s;
                    if (bf) ((u16*)out)[idx] = f2b(o);
                    else ((float*)out)[idx] = o;
                }
            }
        }
    }
}

extern "C" void kernel_launch(void* const* d_in, const int* in_sizes, int n_in,
                              void* d_out, int out_size, void* d_ws, size_t ws_size,
                              hipStream_t stream) {
    const void* node_features = d_in[0];
    const void* lattices      = d_in[1];
    const int* edge_index     = (const int*)d_in[2];
    const int* edge2graph     = (const int*)d_in[3];
    const void* frac_diff     = d_in[4];
    const void* W1e = d_in[5];  const void* b1e = d_in[6];
    const void* W2e = d_in[7];  const void* b2e = d_in[8];
    const void* W1n = d_in[9];  const void* b1n = d_in[10];
    const void* W2n = d_in[11]; const void* b2n = d_in[12];
    const void* ln_g = d_in[13];
    const void* ln_b = d_in[14];

    char* ws = (char*)d_ws;
    size_t off = 0;
    float* agg = (float*)(ws + off);            off += (size_t)N_NODES * H * 4;   // 51.2 MB
    int*   cnt = (int*)(ws + off);              off += (size_t)N_NODES * 4;       // 0.4 MB
    size_t zero_bytes = off;                    // agg + cnt zeroed together
    int*   flag = (int*)(ws + off);             off += 16;
    u16*   h    = (u16*)(ws + off);             off += (size_t)N_NODES * H * 2;   // 25.6 MB
    u16*   latb = (u16*)(ws + off);             off += (size_t)N_GRAPH * 12 * 2;
    u16*   W1p  = (u16*)(ws + off);             off += (size_t)288 * 128 * 2;
    u16*   W2p  = (u16*)(ws + off);             off += (size_t)128 * 128 * 2;
    u16*   W1np = (u16*)(ws + off);             off += (size_t)256 * 128 * 2;
    u16*   W2np = (u16*)(ws + off);             off += (size_t)128 * 128 * 2;

    hipMemsetAsync(agg, 0, zero_bytes, stream);

    probe_kernel<<<1, 256, 0, stream>>>((const unsigned*)node_features, flag);
    ln_kernel<<<(N_NODES + 3) / 4, 256, 0, stream>>>(node_features, ln_g, ln_b, h, flag);
    ltl_kernel<<<(N_GRAPH * 9 + 255) / 256, 256, 0, stream>>>(lattices, latb, flag);
    pack_kernel<<<(9 * 8 * 64 + 255) / 256, 256, 0, stream>>>(W1e, W1p, 268, 9, flag);
    pack_kernel<<<(4 * 8 * 64 + 255) / 256, 256, 0, stream>>>(W2e, W2p, 128, 4, flag);
    pack_kernel<<<(8 * 8 * 64 + 255) / 256, 256, 0, stream>>>(W1n, W1np, 256, 8, flag);
    pack_kernel<<<(4 * 8 * 64 + 255) / 256, 256, 0, stream>>>(W2n, W2np, 128, 4, flag);
    cnt_kernel<<<(N_EDGE + 255) / 256, 256, 0, stream>>>(edge_index, cnt);

    edge_kernel<<<N_EDGE / 64, 256, 0, stream>>>(h, latb, edge_index, edge2graph,
                                                 frac_diff, W1p, W2p, b1e, b2e, agg, flag);
    node_kernel<<<(N_NODES + 63) / 64, 256, 0, stream>>>(h, agg, cnt, node_features,
                                                         W1np, W2np, b1n, b2n, d_out, flag);
}

// Round 3
// 728.392 us; speedup vs baseline: 1.1334x; 1.1334x over previous
//
#include <hip/hip_runtime.h>
#include <stdint.h>

// R3: alias sA/sP LDS buffers (sA dead after layer-1 k-loop) -> LDS 57->40KB (edge),
// 51->35KB (node) -> 4 blocks/CU instead of 2. One extra barrier per kernel.

#define N_NODES 100000
#define N_GRAPH 5000
#define N_EDGE  1000000
#define H 128

typedef unsigned short u16;
typedef __attribute__((ext_vector_type(8))) short short8;
typedef __attribute__((ext_vector_type(4))) float floatx4;

__device__ inline float b2f(u16 x) {
    unsigned u = ((unsigned)x) << 16;
    return __uint_as_float(u);
}
__device__ inline u16 f2b(float f) {
    unsigned u = __float_as_uint(f);
    unsigned r = (u + 0x7FFFu + ((u >> 16) & 1u)) >> 16;  // RNE
    return (u16)r;
}
__device__ inline float silu_f(float x) {
    x = fminf(30.f, fmaxf(-30.f, x));   // also masks any stray NaN/inf
    return x / (1.0f + __expf(-x));
}

// ---------------- dtype probe: flag=1 if inputs are bf16, 0 if fp32 ----------------
__global__ void probe_kernel(const unsigned* __restrict__ nf_raw, int* __restrict__ flag) {
    __shared__ int cnt_s;
    if (threadIdx.x == 0) cnt_s = 0;
    __syncthreads();
    unsigned u = nf_raw[threadIdx.x];
    unsigned e2 = (u >> 7) & 0xFF;   // exponent of LOW-half bf16 if data is bf16 pairs
    int in_range = (e2 >= 90 && e2 <= 160) ? 1 : 0;
    atomicAdd(&cnt_s, in_range);
    __syncthreads();
    if (threadIdx.x == 0) *flag = (cnt_s >= 128) ? 1 : 0;
}

// ---------------- LayerNorm: h = LN(node_features) * g + b, bf16 out ----------------
__global__ void ln_kernel(const void* __restrict__ nf, const void* __restrict__ g,
                          const void* __restrict__ b, u16* __restrict__ h,
                          const int* __restrict__ flagp) {
    int bf = *flagp;
    int row = blockIdx.x * 4 + (threadIdx.x >> 6);
    int lane = threadIdx.x & 63;
    if (row >= N_NODES) return;
    float x0, x1;
    if (bf) {
        unsigned v = ((const unsigned*)nf)[(size_t)row * 64 + lane];
        x0 = b2f((u16)(v & 0xFFFF));
        x1 = b2f((u16)(v >> 16));
    } else {
        const float* p = (const float*)nf + (size_t)row * H + lane * 2;
        x0 = p[0]; x1 = p[1];
    }
    float s1 = x0 + x1, s2 = x0 * x0 + x1 * x1;
    #pragma unroll
    for (int off = 32; off >= 1; off >>= 1) {
        s1 += __shfl_xor(s1, off, 64);
        s2 += __shfl_xor(s2, off, 64);
    }
    float mu = s1 * (1.0f / H);
    float var = s2 * (1.0f / H) - mu * mu;
    float rs = rsqrtf(var + 1e-5f);
    float g0, g1, bb0, bb1;
    if (bf) {
        unsigned gv = ((const unsigned*)g)[lane];
        unsigned bv = ((const unsigned*)b)[lane];
        g0 = b2f((u16)(gv & 0xFFFF)); g1 = b2f((u16)(gv >> 16));
        bb0 = b2f((u16)(bv & 0xFFFF)); bb1 = b2f((u16)(bv >> 16));
    } else {
        g0 = ((const float*)g)[lane * 2]; g1 = ((const float*)g)[lane * 2 + 1];
        bb0 = ((const float*)b)[lane * 2]; bb1 = ((const float*)b)[lane * 2 + 1];
    }
    float y0 = (x0 - mu) * rs * g0 + bb0;
    float y1 = (x1 - mu) * rs * g1 + bb1;
    unsigned o = (unsigned)f2b(y0) | ((unsigned)f2b(y1) << 16);
    *(unsigned*)(h + (size_t)row * H + lane * 2) = o;
}

// ---------------- ltl[g] = L @ L^T flattened to 9, stored bf16 stride 12 ----------------
__global__ void ltl_kernel(const void* __restrict__ lat, u16* __restrict__ latb,
                           const int* __restrict__ flagp) {
    int bf = *flagp;
    int idx = blockIdx.x * 256 + threadIdx.x;
    if (idx >= N_GRAPH * 9) return;
    int gi = idx / 9, ij = idx - gi * 9;
    int i = ij / 3, j = ij - i * 3;
    float s = 0.f;
    if (bf) {
        const u16* Lg = (const u16*)lat + gi * 9;
        #pragma unroll
        for (int k = 0; k < 3; k++) s += b2f(Lg[i * 3 + k]) * b2f(Lg[j * 3 + k]);
    } else {
        const float* Lg = (const float*)lat + gi * 9;
        #pragma unroll
        for (int k = 0; k < 3; k++) s += Lg[i * 3 + k] * Lg[j * 3 + k];
    }
    latb[gi * 12 + ij] = f2b(s);
}

// ---------------- pack W [Ksrc,128] row-major -> MFMA B-fragment layout ----------------
__global__ void pack_kernel(const void* __restrict__ W, u16* __restrict__ out, int Ksrc, int KT,
                            const int* __restrict__ flagp) {
    int bf = *flagp;
    int t = blockIdx.x * 256 + threadIdx.x;
    if (t >= KT * 8 * 64) return;
    int lane = t & 63, nt = (t >> 6) & 7, kt = t >> 9;
    int n = nt * 16 + (lane & 15);
    int kbase = kt * 32 + ((lane >> 4) << 3);
    u16 vals[8];
    #pragma unroll
    for (int j = 0; j < 8; j++) {
        int k = kbase + j;
        if (k >= Ksrc) vals[j] = 0;
        else if (bf) vals[j] = ((const u16*)W)[(size_t)k * H + n];
        else vals[j] = f2b(((const float*)W)[(size_t)k * H + n]);
    }
    uint4 tmp;
    __builtin_memcpy(&tmp, vals, 16);
    *(uint4*)(out + (size_t)t * 8) = tmp;
}

// ---------------- in-degree counts over edge_index[0] ----------------
__global__ void cnt_kernel(const int* __restrict__ ei, int* __restrict__ cnt) {
    int e = blockIdx.x * 256 + threadIdx.x;
    if (e < N_EDGE) atomicAdd(&cnt[ei[e]], 1);
}

// ---------------- fused edge MLP + scatter-add ----------------
#define EKP 296   // A-tile row stride (bf16) for K=288
#define PP  136   // intermediate tile stride

__global__ __launch_bounds__(256, 4) void edge_kernel(
    const u16* __restrict__ h, const u16* __restrict__ latb,
    const int* __restrict__ ei, const int* __restrict__ e2g,
    const void* __restrict__ fd,
    const u16* __restrict__ W1p, const u16* __restrict__ W2p,
    const void* __restrict__ bias1, const void* __restrict__ bias2,
    float* __restrict__ agg, const int* __restrict__ flagp) {
    __shared__ u16 sU[64 * EKP];            // sA and sP alias this buffer
    __shared__ int sSrc[64], sDst[64], sG[64];
    __shared__ float sB1[128], sB2[128];
    u16* sA = sU;
    u16* sP = sU;

    int bf = *flagp;
    int tid = threadIdx.x;
    int lane = tid & 63, w = tid >> 6;
    int e0 = blockIdx.x * 64;

    if (tid < 64) {
        sSrc[tid] = ei[e0 + tid];
        sDst[tid] = ei[N_EDGE + e0 + tid];
        sG[tid] = e2g[e0 + tid];
    }
    if (tid < 128) sB1[tid] = bf ? b2f(((const u16*)bias1)[tid]) : ((const float*)bias1)[tid];
    else sB2[tid - 128] = bf ? b2f(((const u16*)bias2)[tid - 128]) : ((const float*)bias2)[tid - 128];
    __syncthreads();

    // gather hi | hj (16B chunks) from internal bf16 h
    for (int i = tid; i < 2048; i += 256) {
        int row = i >> 5, c = i & 31;
        int node = (c < 16) ? sSrc[row] : sDst[row];
        int cc = c & 15;
        uint4 v = *(const uint4*)(h + (size_t)node * H + cc * 8);
        *(uint4*)(&sA[row * EKP + c * 8]) = v;
    }
    // lat(9) + fd(3) + zero pad(20)
    if (tid < 64) {
        int row = tid;
        int g = sG[row];
        u16* dst = &sA[row * EKP + 256];
        #pragma unroll
        for (int j = 0; j < 9; j++) dst[j] = latb[g * 12 + j];
        if (bf) {
            const u16* f = (const u16*)fd + (size_t)(e0 + row) * 3;
            dst[9] = f[0]; dst[10] = f[1]; dst[11] = f[2];
        } else {
            const float* f = (const float*)fd + (size_t)(e0 + row) * 3;
            dst[9] = f2b(f[0]); dst[10] = f2b(f[1]); dst[11] = f2b(f[2]);
        }
        #pragma unroll
        for (int j = 12; j < 32; j++) dst[j] = 0;
    }
    __syncthreads();

    const short8* W1v = (const short8*)W1p;
    const short8* W2v = (const short8*)W2p;
    int q8 = (lane >> 4) * 8;
    int mrow = lane & 15;
    int q = lane >> 4;

    // ---- layer 1: [64,288] @ [288,128], wave w owns cols w*32..w*32+31 ----
    floatx4 acc[4][2];
    #pragma unroll
    for (int mt = 0; mt < 4; mt++) {
        acc[mt][0] = (floatx4){0.f, 0.f, 0.f, 0.f};
        acc[mt][1] = (floatx4){0.f, 0.f, 0.f, 0.f};
    }
    #pragma unroll
    for (int kt = 0; kt < 9; kt++) {
        short8 bf0 = W1v[(kt * 8 + 2 * w) * 64 + lane];
        short8 bf1 = W1v[(kt * 8 + 2 * w + 1) * 64 + lane];
        #pragma unroll
        for (int mt = 0; mt < 4; mt++) {
            short8 a = *(const short8*)(&sA[(mt * 16 + mrow) * EKP + kt * 32 + q8]);
            acc[mt][0] = __builtin_amdgcn_mfma_f32_16x16x32_bf16(a, bf0, acc[mt][0], 0, 0, 0);
            acc[mt][1] = __builtin_amdgcn_mfma_f32_16x16x32_bf16(a, bf1, acc[mt][1], 0, 0, 0);
        }
    }
    __syncthreads();   // sA dead; sP aliases it

    // epilogue 1: bias + silu -> sP (bf16)
    #pragma unroll
    for (int mt = 0; mt < 4; mt++) {
        #pragma unroll
        for (int nt = 0; nt < 2; nt++) {
            int n = w * 32 + nt * 16 + mrow;
            float bias = sB1[n];
            #pragma unroll
            for (int r = 0; r < 4; r++) {
                int row = mt * 16 + q * 4 + r;
                sP[row * PP + n] = f2b(silu_f(acc[mt][nt][r] + bias));
            }
        }
    }
    __syncthreads();

    // ---- layer 2: [64,128] @ [128,128] ----
    floatx4 acc2[4][2];
    #pragma unroll
    for (int mt = 0; mt < 4; mt++) {
        acc2[mt][0] = (floatx4){0.f, 0.f, 0.f, 0.f};
        acc2[mt][1] = (floatx4){0.f, 0.f, 0.f, 0.f};
    }
    #pragma unroll
    for (int kt = 0; kt < 4; kt++) {
        short8 bf0 = W2v[(kt * 8 + 2 * w) * 64 + lane];
        short8 bf1 = W2v[(kt * 8 + 2 * w + 1) * 64 + lane];
        #pragma unroll
        for (int mt = 0; mt < 4; mt++) {
            short8 a = *(const short8*)(&sP[(mt * 16 + mrow) * PP + kt * 32 + q8]);
            acc2[mt][0] = __builtin_amdgcn_mfma_f32_16x16x32_bf16(a, bf0, acc2[mt][0], 0, 0, 0);
            acc2[mt][1] = __builtin_amdgcn_mfma_f32_16x16x32_bf16(a, bf1, acc2[mt][1], 0, 0, 0);
        }
    }
    // epilogue 2: bias + silu -> atomic scatter into agg[src]
    #pragma unroll
    for (int mt = 0; mt < 4; mt++) {
        #pragma unroll
        for (int nt = 0; nt < 2; nt++) {
            int n = w * 32 + nt * 16 + mrow;
            float bias = sB2[n];
            #pragma unroll
            for (int r = 0; r < 4; r++) {
                int row = mt * 16 + q * 4 + r;
                float s = silu_f(acc2[mt][nt][r] + bias);
                atomicAdd(&agg[(size_t)sSrc[row] * H + n], s);
            }
        }
    }
}

// ---------------- node MLP + residual ----------------
#define NKP 264   // A-tile row stride for K=256

__global__ __launch_bounds__(256, 4) void node_kernel(
    const u16* __restrict__ h, const float* __restrict__ agg, const int* __restrict__ cnt,
    const void* __restrict__ nf,
    const u16* __restrict__ W1p, const u16* __restrict__ W2p,
    const void* __restrict__ bias1, const void* __restrict__ bias2,
    void* __restrict__ out, const int* __restrict__ flagp) {
    __shared__ u16 sU[64 * NKP];            // sA and sP alias
    __shared__ float sB1[128], sB2[128];
    u16* sA = sU;
    u16* sP = sU;

    int bf = *flagp;
    int tid = threadIdx.x;
    int lane = tid & 63, w = tid >> 6;
    int r0 = blockIdx.x * 64;

    if (tid < 128) sB1[tid] = bf ? b2f(((const u16*)bias1)[tid]) : ((const float*)bias1)[tid];
    else sB2[tid - 128] = bf ? b2f(((const u16*)bias2)[tid - 128]) : ((const float*)bias2)[tid - 128];

    // stage h rows (cols 0..127)
    for (int i = tid; i < 1024; i += 256) {
        int row = i >> 4, c = i & 15;
        int gr = r0 + row; if (gr >= N_NODES) gr = N_NODES - 1;
        uint4 v = *(const uint4*)(h + (size_t)gr * H + c * 8);
        *(uint4*)(&sA[row * NKP + c * 8]) = v;
    }
    // stage agg/cnt rows (cols 128..255), fp32 -> bf16
    for (int i = tid; i < 2048; i += 256) {
        int row = i >> 5, c = i & 31;
        int gr = r0 + row; if (gr >= N_NODES) gr = N_NODES - 1;
        int cn = cnt[gr];
        float sc = 1.0f / (float)(cn > 0 ? cn : 1);
        const float* ap = agg + (size_t)gr * H + c * 4;
        u16 vv[4];
        #pragma unroll
        for (int j = 0; j < 4; j++) vv[j] = f2b(ap[j] * sc);
        uint2 tmp;
        __builtin_memcpy(&tmp, vv, 8);
        *(uint2*)(&sA[row * NKP + 128 + c * 4]) = tmp;
    }
    __syncthreads();

    const short8* W1v = (const short8*)W1p;
    const short8* W2v = (const short8*)W2p;
    int q8 = (lane >> 4) * 8;
    int mrow = lane & 15;
    int q = lane >> 4;

    floatx4 acc[4][2];
    #pragma unroll
    for (int mt = 0; mt < 4; mt++) {
        acc[mt][0] = (floatx4){0.f, 0.f, 0.f, 0.f};
        acc[mt][1] = (floatx4){0.f, 0.f, 0.f, 0.f};
    }
    #pragma unroll
    for (int kt = 0; kt < 8; kt++) {
        short8 bf0 = W1v[(kt * 8 + 2 * w) * 64 + lane];
        short8 bf1 = W1v[(kt * 8 + 2 * w + 1) * 64 + lane];
        #pragma unroll
        for (int mt = 0; mt < 4; mt++) {
            short8 a = *(const short8*)(&sA[(mt * 16 + mrow) * NKP + kt * 32 + q8]);
            acc[mt][0] = __builtin_amdgcn_mfma_f32_16x16x32_bf16(a, bf0, acc[mt][0], 0, 0, 0);
            acc[mt][1] = __builtin_amdgcn_mfma_f32_16x16x32_bf16(a, bf1, acc[mt][1], 0, 0, 0);
        }
    }
    __syncthreads();   // sA dead; sP aliases it

    #pragma unroll
    for (int mt = 0; mt < 4; mt++) {
        #pragma unroll
        for (int nt = 0; nt < 2; nt++) {
            int n = w * 32 + nt * 16 + mrow;
            float bias = sB1[n];
            #pragma unroll
            for (int r = 0; r < 4; r++) {
                int row = mt * 16 + q * 4 + r;
                sP[row * PP + n] = f2b(silu_f(acc[mt][nt][r] + bias));
            }
        }
    }
    __syncthreads();

    floatx4 acc2[4][2];
    #pragma unroll
    for (int mt = 0; mt < 4; mt++) {
        acc2[mt][0] = (floatx4){0.f, 0.f, 0.f, 0.f};
        acc2[mt][1] = (floatx4){0.f, 0.f, 0.f, 0.f};
    }
    #pragma unroll
    for (int kt = 0; kt < 4; kt++) {
        short8 bf0 = W2v[(kt * 8 + 2 * w) * 64 + lane];
        short8 bf1 = W2v[(kt * 8 + 2 * w + 1) * 64 + lane];
        #pragma unroll
        for (int mt = 0; mt < 4; mt++) {
            short8 a = *(const short8*)(&sP[(mt * 16 + mrow) * PP + kt * 32 + q8]);
            acc2[mt][0] = __builtin_amdgcn_mfma_f32_16x16x32_bf16(a, bf0, acc2[mt][0], 0, 0, 0);
            acc2[mt][1] = __builtin_amdgcn_mfma_f32_16x16x32_bf16(a, bf1, acc2[mt][1], 0, 0, 0);
        }
    }
    #pragma unroll
    for (int mt = 0; mt < 4; mt++) {
        #pragma unroll
        for (int nt = 0; nt < 2; nt++) {
            int n = w * 32 + nt * 16 + mrow;
            float bias = sB2[n];
            #pragma unroll
            for (int r = 0; r < 4; r++) {
                int row = mt * 16 + q * 4 + r;
                int gr = r0 + row;
                if (gr < N_NODES) {
                    float s = silu_f(acc2[mt][nt][r] + bias);
                    size_t idx = (size_t)gr * H + n;
                    float nv = bf ? b2f(((const u16*)nf)[idx]) : ((const float*)nf)[idx];
                    float o = nv + s;
                    if (bf) ((u16*)out)[idx] = f2b(o);
                    else ((float*)out)[idx] = o;
                }
            }
        }
    }
}

extern "C" void kernel_launch(void* const* d_in, const int* in_sizes, int n_in,
                              void* d_out, int out_size, void* d_ws, size_t ws_size,
                              hipStream_t stream) {
    const void* node_features = d_in[0];
    const void* lattices      = d_in[1];
    const int* edge_index     = (const int*)d_in[2];
    const int* edge2graph     = (const int*)d_in[3];
    const void* frac_diff     = d_in[4];
    const void* W1e = d_in[5];  const void* b1e = d_in[6];
    const void* W2e = d_in[7];  const void* b2e = d_in[8];
    const void* W1n = d_in[9];  const void* b1n = d_in[10];
    const void* W2n = d_in[11]; const void* b2n = d_in[12];
    const void* ln_g = d_in[13];
    const void* ln_b = d_in[14];

    char* ws = (char*)d_ws;
    size_t off = 0;
    float* agg = (float*)(ws + off);            off += (size_t)N_NODES * H * 4;   // 51.2 MB
    int*   cnt = (int*)(ws + off);              off += (size_t)N_NODES * 4;       // 0.4 MB
    size_t zero_bytes = off;                    // agg + cnt zeroed together
    int*   flag = (int*)(ws + off);             off += 16;
    u16*   h    = (u16*)(ws + off);             off += (size_t)N_NODES * H * 2;   // 25.6 MB
    u16*   latb = (u16*)(ws + off);             off += (size_t)N_GRAPH * 12 * 2;
    u16*   W1p  = (u16*)(ws + off);             off += (size_t)288 * 128 * 2;
    u16*   W2p  = (u16*)(ws + off);             off += (size_t)128 * 128 * 2;
    u16*   W1np = (u16*)(ws + off);             off += (size_t)256 * 128 * 2;
    u16*   W2np = (u16*)(ws + off);             off += (size_t)128 * 128 * 2;

    hipMemsetAsync(agg, 0, zero_bytes, stream);

    probe_kernel<<<1, 256, 0, stream>>>((const unsigned*)node_features, flag);
    ln_kernel<<<(N_NODES + 3) / 4, 256, 0, stream>>>(node_features, ln_g, ln_b, h, flag);
    ltl_kernel<<<(N_GRAPH * 9 + 255) / 256, 256, 0, stream>>>(lattices, latb, flag);
    pack_kernel<<<(9 * 8 * 64 + 255) / 256, 256, 0, stream>>>(W1e, W1p, 268, 9, flag);
    pack_kernel<<<(4 * 8 * 64 + 255) / 256, 256, 0, stream>>>(W2e, W2p, 128, 4, flag);
    pack_kernel<<<(8 * 8 * 64 + 255) / 256, 256, 0, stream>>>(W1n, W1np, 256, 8, flag);
    pack_kernel<<<(4 * 8 * 64 + 255) / 256, 256, 0, stream>>>(W2n, W2np, 128, 4, flag);
    cnt_kernel<<<(N_EDGE + 255) / 256, 256, 0, stream>>>(edge_index, cnt);

    edge_kernel<<<N_EDGE / 64, 256, 0, stream>>>(h, latb, edge_index, edge2graph,
                                                 frac_diff, W1p, W2p, b1e, b2e, agg, flag);
    node_kernel<<<(N_NODES + 63) / 64, 256, 0, stream>>>(h, agg, cnt, node_features,
                                                         W1np, W2np, b1n, b2n, d_out, flag);
}

// Round 4
// 712.045 us; speedup vs baseline: 1.1594x; 1.0230x over previous
//
#include <hip/hip_runtime.h>
#include <stdint.h>

// R4: distribute layer-1 GEMM over the concat:
//   ef_pre = U[src] + V[dst] + LG[graph] + fd @ Wfd,  U=h@W1e[0:128], V=h@W1e[128:256],
//   LG[g]=ltl@W1e[256:265]+b1e  (precomputed dense; edge kernel becomes gather+silu+layer2 GEMM).
// U,V live in d_out (dead until node_kernel). Edge LDS ~20KB -> 6+ blocks/CU.

#define N_NODES 100000
#define N_GRAPH 5000
#define N_EDGE  1000000
#define H 128

typedef unsigned short u16;
typedef __attribute__((ext_vector_type(8))) short short8;
typedef __attribute__((ext_vector_type(4))) float floatx4;

__device__ inline float b2f(u16 x) {
    unsigned u = ((unsigned)x) << 16;
    return __uint_as_float(u);
}
__device__ inline u16 f2b(float f) {
    unsigned u = __float_as_uint(f);
    unsigned r = (u + 0x7FFFu + ((u >> 16) & 1u)) >> 16;  // RNE
    return (u16)r;
}
__device__ inline float silu_f(float x) {
    x = fminf(30.f, fmaxf(-30.f, x));
    return x / (1.0f + __expf(-x));
}

// ---------------- dtype probe: flag=1 if inputs are bf16, 0 if fp32 ----------------
__global__ void probe_kernel(const unsigned* __restrict__ nf_raw, int* __restrict__ flag) {
    __shared__ int cnt_s;
    if (threadIdx.x == 0) cnt_s = 0;
    __syncthreads();
    unsigned u = nf_raw[threadIdx.x];
    unsigned e2 = (u >> 7) & 0xFF;
    int in_range = (e2 >= 90 && e2 <= 160) ? 1 : 0;
    atomicAdd(&cnt_s, in_range);
    __syncthreads();
    if (threadIdx.x == 0) *flag = (cnt_s >= 128) ? 1 : 0;
}

// ---------------- LayerNorm: h = LN(node_features) * g + b, bf16 out ----------------
__global__ void ln_kernel(const void* __restrict__ nf, const void* __restrict__ g,
                          const void* __restrict__ b, u16* __restrict__ h,
                          const int* __restrict__ flagp) {
    int bf = *flagp;
    int row = blockIdx.x * 4 + (threadIdx.x >> 6);
    int lane = threadIdx.x & 63;
    if (row >= N_NODES) return;
    float x0, x1;
    if (bf) {
        unsigned v = ((const unsigned*)nf)[(size_t)row * 64 + lane];
        x0 = b2f((u16)(v & 0xFFFF));
        x1 = b2f((u16)(v >> 16));
    } else {
        const float* p = (const float*)nf + (size_t)row * H + lane * 2;
        x0 = p[0]; x1 = p[1];
    }
    float s1 = x0 + x1, s2 = x0 * x0 + x1 * x1;
    #pragma unroll
    for (int off = 32; off >= 1; off >>= 1) {
        s1 += __shfl_xor(s1, off, 64);
        s2 += __shfl_xor(s2, off, 64);
    }
    float mu = s1 * (1.0f / H);
    float var = s2 * (1.0f / H) - mu * mu;
    float rs = rsqrtf(var + 1e-5f);
    float g0, g1, bb0, bb1;
    if (bf) {
        unsigned gv = ((const unsigned*)g)[lane];
        unsigned bv = ((const unsigned*)b)[lane];
        g0 = b2f((u16)(gv & 0xFFFF)); g1 = b2f((u16)(gv >> 16));
        bb0 = b2f((u16)(bv & 0xFFFF)); bb1 = b2f((u16)(bv >> 16));
    } else {
        g0 = ((const float*)g)[lane * 2]; g1 = ((const float*)g)[lane * 2 + 1];
        bb0 = ((const float*)b)[lane * 2]; bb1 = ((const float*)b)[lane * 2 + 1];
    }
    float y0 = (x0 - mu) * rs * g0 + bb0;
    float y1 = (x1 - mu) * rs * g1 + bb1;
    unsigned o = (unsigned)f2b(y0) | ((unsigned)f2b(y1) << 16);
    *(unsigned*)(h + (size_t)row * H + lane * 2) = o;
}

// ---------------- LG[g][c] = b1e[c] + sum_ij ltl(g)_ij * W1e[256+ij][c], bf16 out ----------------
__global__ void lg_kernel(const void* __restrict__ lat, const void* __restrict__ W1e,
                          const void* __restrict__ b1e, u16* __restrict__ LGb,
                          const int* __restrict__ flagp) {
    int bf = *flagp;
    int t = blockIdx.x * 256 + threadIdx.x;
    if (t >= N_GRAPH * 64) return;
    int g = t >> 6, cp = (t & 63) * 2;
    float L[9];
    #pragma unroll
    for (int k = 0; k < 9; k++)
        L[k] = bf ? b2f(((const u16*)lat)[g * 9 + k]) : ((const float*)lat)[g * 9 + k];
    float a0 = bf ? b2f(((const u16*)b1e)[cp])     : ((const float*)b1e)[cp];
    float a1 = bf ? b2f(((const u16*)b1e)[cp + 1]) : ((const float*)b1e)[cp + 1];
    #pragma unroll
    for (int i = 0; i < 3; i++) {
        #pragma unroll
        for (int j = 0; j < 3; j++) {
            float lt = L[i*3] * L[j*3] + L[i*3+1] * L[j*3+1] + L[i*3+2] * L[j*3+2];
            int r = 256 + i * 3 + j;
            float w0 = bf ? b2f(((const u16*)W1e)[(size_t)r * H + cp])     : ((const float*)W1e)[(size_t)r * H + cp];
            float w1 = bf ? b2f(((const u16*)W1e)[(size_t)r * H + cp + 1]) : ((const float*)W1e)[(size_t)r * H + cp + 1];
            a0 += lt * w0;
            a1 += lt * w1;
        }
    }
    LGb[(size_t)g * H + cp] = f2b(a0);
    LGb[(size_t)g * H + cp + 1] = f2b(a1);
}

// ---------------- pack W rows [k0, k0+KT*32) of [Ktot,128] -> MFMA B-fragment layout ----------------
__global__ void pack_kernel(const void* __restrict__ W, u16* __restrict__ out, int k0, int Ktot, int KT,
                            const int* __restrict__ flagp) {
    int bf = *flagp;
    int t = blockIdx.x * 256 + threadIdx.x;
    if (t >= KT * 8 * 64) return;
    int lane = t & 63, nt = (t >> 6) & 7, kt = t >> 9;
    int n = nt * 16 + (lane & 15);
    int kbase = k0 + kt * 32 + ((lane >> 4) << 3);
    u16 vals[8];
    #pragma unroll
    for (int j = 0; j < 8; j++) {
        int k = kbase + j;
        if (k >= Ktot) vals[j] = 0;
        else if (bf) vals[j] = ((const u16*)W)[(size_t)k * H + n];
        else vals[j] = f2b(((const float*)W)[(size_t)k * H + n]);
    }
    uint4 tmp;
    __builtin_memcpy(&tmp, vals, 16);
    *(uint4*)(out + (size_t)t * 8) = tmp;
}

// ---------------- in-degree counts over edge_index[0] ----------------
__global__ void cnt_kernel(const int* __restrict__ ei, int* __restrict__ cnt) {
    int e = blockIdx.x * 256 + threadIdx.x;
    if (e < N_EDGE) atomicAdd(&cnt[ei[e]], 1);
}

// ---------------- uv: U = h @ W1e[0:128], V = h @ W1e[128:256], bf16, no bias/act ----------------
#define UVP 136
__global__ __launch_bounds__(256, 4) void uv_kernel(
    const u16* __restrict__ h, const u16* __restrict__ Wtp, const u16* __restrict__ Wmp,
    u16* __restrict__ U, u16* __restrict__ V) {
    __shared__ u16 sA[64 * UVP];
    int tid = threadIdx.x;
    int lane = tid & 63, w = tid >> 6;
    int r0 = blockIdx.x * 64;

    for (int i = tid; i < 1024; i += 256) {
        int row = i >> 4, c = i & 15;
        int gr = r0 + row; if (gr >= N_NODES) gr = N_NODES - 1;
        uint4 v = *(const uint4*)(h + (size_t)gr * H + c * 8);
        *(uint4*)(&sA[row * UVP + c * 8]) = v;
    }
    __syncthreads();

    const short8* Wt = (const short8*)Wtp;
    const short8* Wm = (const short8*)Wmp;
    int q8 = (lane >> 4) * 8;
    int mrow = lane & 15;
    int q = lane >> 4;

    floatx4 aU[4][2], aV[4][2];
    #pragma unroll
    for (int mt = 0; mt < 4; mt++) {
        aU[mt][0] = (floatx4){0,0,0,0}; aU[mt][1] = (floatx4){0,0,0,0};
        aV[mt][0] = (floatx4){0,0,0,0}; aV[mt][1] = (floatx4){0,0,0,0};
    }
    #pragma unroll
    for (int kt = 0; kt < 4; kt++) {
        short8 bu0 = Wt[(kt * 8 + 2 * w) * 64 + lane];
        short8 bu1 = Wt[(kt * 8 + 2 * w + 1) * 64 + lane];
        short8 bv0 = Wm[(kt * 8 + 2 * w) * 64 + lane];
        short8 bv1 = Wm[(kt * 8 + 2 * w + 1) * 64 + lane];
        #pragma unroll
        for (int mt = 0; mt < 4; mt++) {
            short8 a = *(const short8*)(&sA[(mt * 16 + mrow) * UVP + kt * 32 + q8]);
            aU[mt][0] = __builtin_amdgcn_mfma_f32_16x16x32_bf16(a, bu0, aU[mt][0], 0, 0, 0);
            aU[mt][1] = __builtin_amdgcn_mfma_f32_16x16x32_bf16(a, bu1, aU[mt][1], 0, 0, 0);
            aV[mt][0] = __builtin_amdgcn_mfma_f32_16x16x32_bf16(a, bv0, aV[mt][0], 0, 0, 0);
            aV[mt][1] = __builtin_amdgcn_mfma_f32_16x16x32_bf16(a, bv1, aV[mt][1], 0, 0, 0);
        }
    }
    #pragma unroll
    for (int mt = 0; mt < 4; mt++) {
        #pragma unroll
        for (int nt = 0; nt < 2; nt++) {
            int n = w * 32 + nt * 16 + mrow;
            #pragma unroll
            for (int r = 0; r < 4; r++) {
                int gr = r0 + mt * 16 + q * 4 + r;
                if (gr < N_NODES) {
                    U[(size_t)gr * H + n] = f2b(aU[mt][nt][r]);
                    V[(size_t)gr * H + n] = f2b(aV[mt][nt][r]);
                }
            }
        }
    }
}

// ---------------- fused edge: gather U/V/LG + fd-term + silu -> layer2 GEMM -> atomic scatter ----------------
#define PP 136

__global__ __launch_bounds__(256, 6) void edge_kernel(
    const u16* __restrict__ U, const u16* __restrict__ V, const u16* __restrict__ LGb,
    const int* __restrict__ ei, const int* __restrict__ e2g,
    const void* __restrict__ fd, const void* __restrict__ W1e,
    const u16* __restrict__ W2p, const void* __restrict__ bias2,
    float* __restrict__ agg, const int* __restrict__ flagp) {
    __shared__ u16 sP[64 * PP];
    __shared__ int sSrc[64], sDst[64], sG[64];
    __shared__ float sFd[192];
    __shared__ float sB2[128];

    int bf = *flagp;
    int tid = threadIdx.x;
    int lane = tid & 63, w = tid >> 6;
    int e0 = blockIdx.x * 64;

    if (tid < 64) {
        sSrc[tid] = ei[e0 + tid];
        sDst[tid] = ei[N_EDGE + e0 + tid];
        sG[tid] = e2g[e0 + tid];
    }
    if (tid < 128) sB2[tid] = bf ? b2f(((const u16*)bias2)[tid]) : ((const float*)bias2)[tid];
    if (tid < 192) sFd[tid] = bf ? b2f(((const u16*)fd)[(size_t)e0 * 3 + tid])
                                 : ((const float*)fd)[(size_t)e0 * 3 + tid];

    // Wfd = W1e rows 265..267, cols c..c+3 (fixed per thread)
    int c = (tid & 31) * 4;
    float wf[3][4];
    #pragma unroll
    for (int k = 0; k < 3; k++)
        #pragma unroll
        for (int j = 0; j < 4; j++)
            wf[k][j] = bf ? b2f(((const u16*)W1e)[(size_t)(265 + k) * H + c + j])
                          : ((const float*)W1e)[(size_t)(265 + k) * H + c + j];
    __syncthreads();

    // gather + fd-term + silu -> sP
    for (int i = tid; i < 2048; i += 256) {
        int row = i >> 5;
        int s = sSrc[row], d = sDst[row], g = sG[row];
        uint2 uu = *(const uint2*)(U + (size_t)s * H + c);
        uint2 vv = *(const uint2*)(V + (size_t)d * H + c);
        uint2 gg = *(const uint2*)(LGb + (size_t)g * H + c);
        float f0 = sFd[row * 3], f1 = sFd[row * 3 + 1], f2v = sFd[row * 3 + 2];
        unsigned uw[2] = {uu.x, uu.y}, vw[2] = {vv.x, vv.y}, gw[2] = {gg.x, gg.y};
        u16 o[4];
        #pragma unroll
        for (int j = 0; j < 4; j++) {
            float uvj = b2f((u16)(uw[j >> 1] >> (16 * (j & 1))))
                      + b2f((u16)(vw[j >> 1] >> (16 * (j & 1))))
                      + b2f((u16)(gw[j >> 1] >> (16 * (j & 1))));
            float val = uvj + f0 * wf[0][j] + f1 * wf[1][j] + f2v * wf[2][j];
            o[j] = f2b(silu_f(val));
        }
        uint2 packed;
        __builtin_memcpy(&packed, o, 8);
        *(uint2*)(&sP[row * PP + c]) = packed;
    }
    __syncthreads();

    const short8* W2v = (const short8*)W2p;
    int q8 = (lane >> 4) * 8;
    int mrow = lane & 15;
    int q = lane >> 4;

    // layer 2: [64,128] @ [128,128]
    floatx4 acc2[4][2];
    #pragma unroll
    for (int mt = 0; mt < 4; mt++) {
        acc2[mt][0] = (floatx4){0,0,0,0};
        acc2[mt][1] = (floatx4){0,0,0,0};
    }
    #pragma unroll
    for (int kt = 0; kt < 4; kt++) {
        short8 bf0 = W2v[(kt * 8 + 2 * w) * 64 + lane];
        short8 bf1 = W2v[(kt * 8 + 2 * w + 1) * 64 + lane];
        #pragma unroll
        for (int mt = 0; mt < 4; mt++) {
            short8 a = *(const short8*)(&sP[(mt * 16 + mrow) * PP + kt * 32 + q8]);
            acc2[mt][0] = __builtin_amdgcn_mfma_f32_16x16x32_bf16(a, bf0, acc2[mt][0], 0, 0, 0);
            acc2[mt][1] = __builtin_amdgcn_mfma_f32_16x16x32_bf16(a, bf1, acc2[mt][1], 0, 0, 0);
        }
    }
    // bias + silu -> atomic scatter into agg[src]
    #pragma unroll
    for (int mt = 0; mt < 4; mt++) {
        #pragma unroll
        for (int nt = 0; nt < 2; nt++) {
            int n = w * 32 + nt * 16 + mrow;
            float bias = sB2[n];
            #pragma unroll
            for (int r = 0; r < 4; r++) {
                int row = mt * 16 + q * 4 + r;
                float s = silu_f(acc2[mt][nt][r] + bias);
                atomicAdd(&agg[(size_t)sSrc[row] * H + n], s);
            }
        }
    }
}

// ---------------- node MLP + residual ----------------
#define NKP 264

__global__ __launch_bounds__(256, 4) void node_kernel(
    const u16* __restrict__ h, const float* __restrict__ agg, const int* __restrict__ cnt,
    const void* __restrict__ nf,
    const u16* __restrict__ W1p, const u16* __restrict__ W2p,
    const void* __restrict__ bias1, const void* __restrict__ bias2,
    void* __restrict__ out, const int* __restrict__ flagp) {
    __shared__ u16 sU[64 * NKP];
    __shared__ float sB1[128], sB2[128];
    u16* sA = sU;
    u16* sP = sU;

    int bf = *flagp;
    int tid = threadIdx.x;
    int lane = tid & 63, w = tid >> 6;
    int r0 = blockIdx.x * 64;

    if (tid < 128) sB1[tid] = bf ? b2f(((const u16*)bias1)[tid]) : ((const float*)bias1)[tid];
    else sB2[tid - 128] = bf ? b2f(((const u16*)bias2)[tid - 128]) : ((const float*)bias2)[tid - 128];

    for (int i = tid; i < 1024; i += 256) {
        int row = i >> 4, c = i & 15;
        int gr = r0 + row; if (gr >= N_NODES) gr = N_NODES - 1;
        uint4 v = *(const uint4*)(h + (size_t)gr * H + c * 8);
        *(uint4*)(&sA[row * NKP + c * 8]) = v;
    }
    for (int i = tid; i < 2048; i += 256) {
        int row = i >> 5, c = i & 31;
        int gr = r0 + row; if (gr >= N_NODES) gr = N_NODES - 1;
        int cn = cnt[gr];
        float sc = 1.0f / (float)(cn > 0 ? cn : 1);
        const float* ap = agg + (size_t)gr * H + c * 4;
        u16 vv[4];
        #pragma unroll
        for (int j = 0; j < 4; j++) vv[j] = f2b(ap[j] * sc);
        uint2 tmp;
        __builtin_memcpy(&tmp, vv, 8);
        *(uint2*)(&sA[row * NKP + 128 + c * 4]) = tmp;
    }
    __syncthreads();

    const short8* W1v = (const short8*)W1p;
    const short8* W2v = (const short8*)W2p;
    int q8 = (lane >> 4) * 8;
    int mrow = lane & 15;
    int q = lane >> 4;

    floatx4 acc[4][2];
    #pragma unroll
    for (int mt = 0; mt < 4; mt++) {
        acc[mt][0] = (floatx4){0,0,0,0};
        acc[mt][1] = (floatx4){0,0,0,0};
    }
    #pragma unroll
    for (int kt = 0; kt < 8; kt++) {
        short8 bf0 = W1v[(kt * 8 + 2 * w) * 64 + lane];
        short8 bf1 = W1v[(kt * 8 + 2 * w + 1) * 64 + lane];
        #pragma unroll
        for (int mt = 0; mt < 4; mt++) {
            short8 a = *(const short8*)(&sA[(mt * 16 + mrow) * NKP + kt * 32 + q8]);
            acc[mt][0] = __builtin_amdgcn_mfma_f32_16x16x32_bf16(a, bf0, acc[mt][0], 0, 0, 0);
            acc[mt][1] = __builtin_amdgcn_mfma_f32_16x16x32_bf16(a, bf1, acc[mt][1], 0, 0, 0);
        }
    }
    __syncthreads();

    #pragma unroll
    for (int mt = 0; mt < 4; mt++) {
        #pragma unroll
        for (int nt = 0; nt < 2; nt++) {
            int n = w * 32 + nt * 16 + mrow;
            float bias = sB1[n];
            #pragma unroll
            for (int r = 0; r < 4; r++) {
                int row = mt * 16 + q * 4 + r;
                sP[row * PP + n] = f2b(silu_f(acc[mt][nt][r] + bias));
            }
        }
    }
    __syncthreads();

    floatx4 acc2[4][2];
    #pragma unroll
    for (int mt = 0; mt < 4; mt++) {
        acc2[mt][0] = (floatx4){0,0,0,0};
        acc2[mt][1] = (floatx4){0,0,0,0};
    }
    #pragma unroll
    for (int kt = 0; kt < 4; kt++) {
        short8 bf0 = W2v[(kt * 8 + 2 * w) * 64 + lane];
        short8 bf1 = W2v[(kt * 8 + 2 * w + 1) * 64 + lane];
        #pragma unroll
        for (int mt = 0; mt < 4; mt++) {
            short8 a = *(const short8*)(&sP[(mt * 16 + mrow) * PP + kt * 32 + q8]);
            acc2[mt][0] = __builtin_amdgcn_mfma_f32_16x16x32_bf16(a, bf0, acc2[mt][0], 0, 0, 0);
            acc2[mt][1] = __builtin_amdgcn_mfma_f32_16x16x32_bf16(a, bf1, acc2[mt][1], 0, 0, 0);
        }
    }
    #pragma unroll
    for (int mt = 0; mt < 4; mt++) {
        #pragma unroll
        for (int nt = 0; nt < 2; nt++) {
            int n = w * 32 + nt * 16 + mrow;
            float bias = sB2[n];
            #pragma unroll
            for (int r = 0; r < 4; r++) {
                int row = mt * 16 + q * 4 + r;
                int gr = r0 + row;
                if (gr < N_NODES) {
                    float s = silu_f(acc2[mt][nt][r] + bias);
                    size_t idx = (size_t)gr * H + n;
                    float nv = bf ? b2f(((const u16*)nf)[idx]) : ((const float*)nf)[idx];
                    float o = nv + s;
                    if (bf) ((u16*)out)[idx] = f2b(o);
                    else ((float*)out)[idx] = o;
                }
            }
        }
    }
}

extern "C" void kernel_launch(void* const* d_in, const int* in_sizes, int n_in,
                              void* d_out, int out_size, void* d_ws, size_t ws_size,
                              hipStream_t stream) {
    const void* node_features = d_in[0];
    const void* lattices      = d_in[1];
    const int* edge_index     = (const int*)d_in[2];
    const int* edge2graph     = (const int*)d_in[3];
    const void* frac_diff     = d_in[4];
    const void* W1e = d_in[5];  const void* b1e = d_in[6];
    const void* W2e = d_in[7];  const void* b2e = d_in[8];
    const void* W1n = d_in[9];  const void* b1n = d_in[10];
    const void* W2n = d_in[11]; const void* b2n = d_in[12];
    const void* ln_g = d_in[13];
    const void* ln_b = d_in[14];

    char* ws = (char*)d_ws;
    size_t off = 0;
    float* agg = (float*)(ws + off);            off += (size_t)N_NODES * H * 4;   // 51.2 MB
    int*   cnt = (int*)(ws + off);              off += (size_t)N_NODES * 4;
    size_t zero_bytes = off;
    int*   flag = (int*)(ws + off);             off += 16;
    u16*   h    = (u16*)(ws + off);             off += (size_t)N_NODES * H * 2;   // 25.6 MB
    u16*   LGb  = (u16*)(ws + off);             off += (size_t)N_GRAPH * H * 2;   // 1.28 MB
    u16*   W1tp = (u16*)(ws + off);             off += (size_t)128 * 128 * 2;
    u16*   W1mp = (u16*)(ws + off);             off += (size_t)128 * 128 * 2;
    u16*   W2p  = (u16*)(ws + off);             off += (size_t)128 * 128 * 2;
    u16*   W1np = (u16*)(ws + off);             off += (size_t)256 * 128 * 2;
    u16*   W2np = (u16*)(ws + off);             off += (size_t)128 * 128 * 2;

    // U, V live in d_out: [N,128] bf16 each = 25.6 MB + 25.6 MB = exactly out's 51.2 MB.
    // d_out isn't written (node_kernel) until edge_kernel is done with U,V.
    u16* U = (u16*)d_out;
    u16* V = (u16*)d_out + (size_t)N_NODES * H;

    hipMemsetAsync(agg, 0, zero_bytes, stream);

    probe_kernel<<<1, 256, 0, stream>>>((const unsigned*)node_features, flag);
    ln_kernel<<<(N_NODES + 3) / 4, 256, 0, stream>>>(node_features, ln_g, ln_b, h, flag);
    lg_kernel<<<(N_GRAPH * 64 + 255) / 256, 256, 0, stream>>>(lattices, W1e, b1e, LGb, flag);
    pack_kernel<<<(4 * 8 * 64 + 255) / 256, 256, 0, stream>>>(W1e, W1tp, 0, 268, 4, flag);
    pack_kernel<<<(4 * 8 * 64 + 255) / 256, 256, 0, stream>>>(W1e, W1mp, 128, 268, 4, flag);
    pack_kernel<<<(4 * 8 * 64 + 255) / 256, 256, 0, stream>>>(W2e, W2p, 0, 128, 4, flag);
    pack_kernel<<<(8 * 8 * 64 + 255) / 256, 256, 0, stream>>>(W1n, W1np, 0, 256, 8, flag);
    pack_kernel<<<(4 * 8 * 64 + 255) / 256, 256, 0, stream>>>(W2n, W2np, 0, 128, 4, flag);
    cnt_kernel<<<(N_EDGE + 255) / 256, 256, 0, stream>>>(edge_index, cnt);

    uv_kernel<<<(N_NODES + 63) / 64, 256, 0, stream>>>(h, W1tp, W1mp, U, V);
    edge_kernel<<<N_EDGE / 64, 256, 0, stream>>>(U, V, LGb, edge_index, edge2graph,
                                                 frac_diff, W1e, W2p, b2e, agg, flag);
    node_kernel<<<(N_NODES + 63) / 64, 256, 0, stream>>>(h, agg, cnt, node_features,
                                                         W1np, W2np, b1n, b2n, d_out, flag);
}